// Round 1
// baseline (176.848 us; speedup 1.0000x reference)
//
#include <hip/hip_runtime.h>

// NCE loss, fused. N=16384 rows, E=512, V=50257, NR=100 shared noise words.
// loss = mean_rows[ softplus(-x_t) + sum_j softplus(x_nj) ],
//   x = <inp_row, emb_word> + bias_w - log V - logp_noise_w - log NR
//
// R7: memory-hygiene pass on top of R6's occupancy/MLP balance.
//  - Non-temporal (nt) loads for the two single-use HBM streams (inp rows,
//    target-emb gathers): 67 MB of streaming data no longer evicts the one
//    REUSED working set (114 KB bf16 noise tile, read by all 1024 blocks =
//    117 MB of L2 traffic) from the 4 MB per-XCD L2s.
//  - Prologue reordered: 16 long-latency A/T loads issued first, 7 L2-resident
//    B loads second, small sBn/sTb prep (dependent gather chains) last so it
//    overlaps with the in-flight bulk loads.
//  - Same R6 structure otherwise: 1024 blocks x 256 thr, 16 rows/block,
//    4-way K-split (K=128/wave), A/T prefetch depth 2,
//    __launch_bounds__(256,4) -> all 1024 blocks resident (16 waves/CU).

#define E_SZ   512
#define NROWS  16384
#define NRn    100
#define NWp    112
#define MT     16
#define NBLK   (NROWS / MT)

typedef __attribute__((ext_vector_type(8))) short short8;
typedef __attribute__((ext_vector_type(4))) float f32x4;

#define NTL 15.430077572997398f   // log(V) + log(NR)

__device__ __forceinline__ unsigned int pack2(float a, float b) {
    unsigned int ua = __float_as_uint(a) + 0x8000u;
    unsigned int ub = __float_as_uint(b) + 0x8000u;
    return __builtin_amdgcn_perm(ub, ua, 0x07060302u); // [ua.b2,ua.b3,ub.b2,ub.b3]
}
__device__ __forceinline__ float softplus(float x) {
    return fmaxf(x, 0.f) + log1pf(__expf(-fabsf(x)));
}
__device__ __forceinline__ short8 cvt8(f32x4 x0, f32x4 x1) {
    union { unsigned int u[4]; short8 s; } r;
    r.u[0] = pack2(x0[0], x0[1]);
    r.u[1] = pack2(x0[2], x0[3]);
    r.u[2] = pack2(x1[0], x1[1]);
    r.u[3] = pack2(x1[2], x1[3]);
    return r.s;
}
// 16B non-temporal load: keeps the streaming A/T traffic from evicting the
// L2-resident noise tile. Emits global_load_dwordx4 ... nt.
__device__ __forceinline__ f32x4 ntld(const float* p) {
    return __builtin_nontemporal_load((const f32x4*)p);
}

// ---- kernel 1: noise rows f32 -> bf16 (nB[kg][word][8], kg=k>>3) + out=0 ----
__global__ __launch_bounds__(128)
void prep_noise(const float* __restrict__ emb, const float* __restrict__ bias,
                const float* __restrict__ lpn, const int* __restrict__ nidx,
                unsigned short* __restrict__ nB,   // (64, 112, 8) bf16
                float* __restrict__ nBn,           // (112,)
                float* __restrict__ out)
{
    const int j = blockIdx.x;          // word slot 0..111
    const int t = threadIdx.x;         // 0..127, elems 4t..4t+3
    const int idx = (j < NRn) ? nidx[j] : 0;
    f32x4 v = {0.f, 0.f, 0.f, 0.f};
    if (j < NRn) v = ntld(emb + (size_t)idx * E_SZ + t * 4);
    unsigned int u0 = pack2(v[0], v[1]);
    unsigned int u1 = pack2(v[2], v[3]);
    const int kg  = t >> 1;            // (4t)>>3
    const int off = (t & 1) * 4;       // (4t)&7
    *(uint2*)(nB + ((size_t)kg * NWp + j) * 8 + off) = make_uint2(u0, u1);
    if (t == 0)
        nBn[j] = (j < NRn) ? (bias[idx] - NTL - lpn[idx]) : 0.f;
    if (j == 0 && t == 0)
        out[0] = 0.f;                  // memset folded in; main kernel ordered after
}

// ---- kernel 2: fused scores + softplus + reduction ----
__global__ __launch_bounds__(256, 4)
void nce_loss_kernel(const float* __restrict__ inp,   // (N, E)
                     const float* __restrict__ emb,   // (V, E)
                     const float* __restrict__ bias,  // (V,)
                     const float* __restrict__ lpn,   // (V,)
                     const int*   __restrict__ target,// (N,)
                     const unsigned short* __restrict__ nB,  // (64,112,8) bf16
                     const float* __restrict__ nBn,   // (112,)
                     float* __restrict__ out)
{
    const int t    = threadIdx.x;
    const int w    = t >> 6;
    const int lane = t & 63;
    const int c    = lane & 15;
    const int q    = lane >> 4;
    const int r0   = blockIdx.x * MT;

    __shared__ float sAcc[4 * 2048];   // per-wave disjoint combine slabs, 32 KB
    __shared__ float sBn[NWp];
    __shared__ float sTb[MT];
    __shared__ float sWs[4];

    // fragment pointers (A/B layout: [idx=lane&15][k=q*8+j])
    const int tgc = target[r0 + c];
    const int kb  = w * 128 + q * 8;   // wave K-slice base + lane k-offset
    const float* pA = inp + (size_t)(r0 + c) * E_SZ + kb;
    const float* pT = emb + (size_t)tgc * E_SZ + kb;
    // B base for step ks: nB + ((w*16+q + ks*4)*112 + c)*8 ; tile ti at +ti*128
    const unsigned short* pB = nB + ((size_t)(w * 16 + q) * NWp + c) * 8;

    // ---- prologue: long-latency A/T streams first (nt), L2-resident B second ----
    f32x4 a[2][2], tt[2][2];
#pragma unroll
    for (int p = 0; p < 2; ++p) {
        a[p][0]  = ntld(pA + p * 32);
        a[p][1]  = ntld(pA + p * 32 + 4);
        tt[p][0] = ntld(pT + p * 32);
        tt[p][1] = ntld(pT + p * 32 + 4);
    }
    short8 curB[7];
#pragma unroll
    for (int ti = 0; ti < 7; ++ti) curB[ti] = *(const short8*)(pB + ti * 128);

    // small LDS prep after the bulk loads are in flight (first read is after
    // the combine __syncthreads, so no extra barrier needed here)
    if (t < NWp) sBn[t] = nBn[t];
    if (t < MT) {
        int tg = target[r0 + t];
        sTb[t] = bias[tg] - NTL - lpn[tg];
    }

    f32x4 accN[7];
    f32x4 accT = {0.f, 0.f, 0.f, 0.f};
#pragma unroll
    for (int ti = 0; ti < 7; ++ti) accN[ti] = {0.f, 0.f, 0.f, 0.f};

#pragma unroll
    for (int ks = 0; ks < 4; ++ks) {
        const int pb = ks & 1;
        short8 A = cvt8(a[pb][0], a[pb][1]);
        short8 T = cvt8(tt[pb][0], tt[pb][1]);
        short8 Bv[7];
#pragma unroll
        for (int ti = 0; ti < 7; ++ti) Bv[ti] = curB[ti];

        // refill: A/T for step ks+2 into the buffer just consumed; B for ks+1
        if (ks < 2) {
            a[pb][0]  = ntld(pA + (ks + 2) * 32);
            a[pb][1]  = ntld(pA + (ks + 2) * 32 + 4);
            tt[pb][0] = ntld(pT + (ks + 2) * 32);
            tt[pb][1] = ntld(pT + (ks + 2) * 32 + 4);
        }
        if (ks < 3) {
            const unsigned short* pBn = pB + (size_t)(ks + 1) * 4 * NWp * 8;
#pragma unroll
            for (int ti = 0; ti < 7; ++ti)
                curB[ti] = *(const short8*)(pBn + ti * 128);
        }

        accT = __builtin_amdgcn_mfma_f32_16x16x32_bf16(A, T, accT, 0, 0, 0);
#pragma unroll
        for (int ti = 0; ti < 7; ++ti)
            accN[ti] = __builtin_amdgcn_mfma_f32_16x16x32_bf16(A, Bv[ti], accN[ti], 0, 0, 0);
    }

    // ---- combine k-split partials: disjoint slabs, no atomics ----
    float* slab = sAcc + w * 2048;     // slot = tile*256 + reg*64 + lane
#pragma unroll
    for (int ti = 0; ti < 7; ++ti)
#pragma unroll
        for (int r = 0; r < 4; ++r)
            slab[ti * 256 + r * 64 + lane] = accN[ti][r];
#pragma unroll
    for (int r = 0; r < 4; ++r)
        slab[7 * 256 + r * 64 + lane] = accT[r];
    __syncthreads();

    // ---- epilogue: C/D layout col=lane&15, row=(lane>>4)*4+reg ----
    const int ereg = w;
    const int col  = lane & 15;
    const int erow = (lane >> 4) * 4 + ereg;
    float ll = 0.f;
#pragma unroll
    for (int i = 0; i < 7; ++i) {
        int word = i * 16 + col;
        float v = sAcc[i * 256 + t] + sAcc[2048 + i * 256 + t]
                + sAcc[4096 + i * 256 + t] + sAcc[6144 + i * 256 + t];
        if (word < NRn)
            ll += softplus(v + sBn[word]);
    }
    {
        float v = sAcc[7 * 256 + t] + sAcc[2048 + 7 * 256 + t]
                + sAcc[4096 + 7 * 256 + t] + sAcc[6144 + 7 * 256 + t];
        if (col == erow)
            ll += softplus(-(v + sTb[erow]));
    }

#pragma unroll
    for (int off = 32; off > 0; off >>= 1) ll += __shfl_down(ll, off);
    if (lane == 0) sWs[w] = ll;
    __syncthreads();
    if (t == 0) {
        float s = (sWs[0] + sWs[1]) + (sWs[2] + sWs[3]);
        atomicAdd(out, s * (1.f / (float)NROWS));
    }
}

extern "C" void kernel_launch(void* const* d_in, const int* in_sizes, int n_in,
                              void* d_out, int out_size, void* d_ws, size_t ws_size,
                              hipStream_t stream) {
    const float* inp    = (const float*)d_in[0];
    const float* emb    = (const float*)d_in[1];
    const float* bias   = (const float*)d_in[2];
    const float* lpn    = (const float*)d_in[3];
    const int*   target = (const int*)d_in[4];
    const int*   nidx   = (const int*)d_in[5];
    float* out = (float*)d_out;

    unsigned short* nB  = (unsigned short*)d_ws;              // 64*112*8*2 = 114688 B
    float*          nBn = (float*)((char*)d_ws + (size_t)64 * NWp * 8 * 2);

    prep_noise<<<NWp, 128, 0, stream>>>(emb, bias, lpn, nidx, nB, nBn, out);
    nce_loss_kernel<<<NBLK, 256, 0, stream>>>(inp, emb, bias, lpn, target, nB, nBn, out);
}